// Round 7
// baseline (192.205 us; speedup 1.0000x reference)
//
#include <hip/hip_runtime.h>
#include <hip/hip_bf16.h>

#define B_    16
#define CIN_  128
#define COUT_ 256
#define H_    80
#define W_    80
#define HO_   40
#define WO_   40
#define KK_   9
#define SK_   1152      // CIN_*KK_
#define NPIX_ 25600     // B_*HO_*WO_
#define NKS_  36        // K / 32

typedef __attribute__((ext_vector_type(8))) short short8;
typedef __attribute__((ext_vector_type(4))) float floatx4;

__device__ __forceinline__ unsigned short f2bu(float v) {
  __hip_bfloat16 h = __float2bfloat16(v);
  return *reinterpret_cast<unsigned short*>(&h);
}
__device__ __forceinline__ float bu2f(unsigned short u) {
  return __uint_as_float(((unsigned)u) << 16);
}
__device__ __forceinline__ unsigned int pk2(float a, float b) {
  return (unsigned)f2bu(a) | ((unsigned)f2bu(b) << 16);
}
// async global->LDS DMA, 16B per lane. LDS dest = wave-uniform base + lane*16.
__device__ __forceinline__ void gl_lds16(const unsigned short* g, unsigned short* l) {
  __builtin_amdgcn_global_load_lds(
      (const __attribute__((address_space(1))) unsigned int*)(const void*)g,
      (__attribute__((address_space(3))) unsigned int*)(void*)l, 16, 0, 0);
}

// ------------------------------------------------- KT: pack weights for MFMA
// Layout v4 (rounds 3/4 verified-passing): Apk[ks(36)][m(256)][slot(4)][j(8)],
// slot of row m holds k-quad qd = (slot - (m>>1)) & 3 (bank rotation ->
// conflict-free ds_read_b128 of A fragments). Also zeroes BN accumulators.
__global__ __launch_bounds__(256) void k_pack(const float* __restrict__ dw,
                                              unsigned short* __restrict__ Apk,
                                              float* __restrict__ accum) {
  int t = blockIdx.x * 256 + threadIdx.x;   // 0..294911
  if (t < 2 * COUT_) accum[t] = 0.f;
  int j  = t & 7;
  int sl = (t >> 3) & 3;
  int m  = (t >> 5) & 255;
  int ks = t >> 13;
  int qd = (sl - (m >> 1)) & 3;
  int k  = ks * 32 + qd * 8 + j;
  int kk = k >> 7, ci = k & 127;
  Apk[t] = f2bu(dw[m * SK_ + ci * KK_ + kk]);
}

// --------------- KC v2: x -> channels-last bf16 + fused offset conv
// (verified) XCD-affine by b (b%8 == xcd of writer); packed-pair LDS tile.
__global__ __launch_bounds__(256) void k_cl(const float* __restrict__ x,
                                            const float* __restrict__ ow,
                                            const float* __restrict__ ob,
                                            unsigned short* __restrict__ xcl,
                                            float* __restrict__ off) {
  __shared__ unsigned int ts[CIN_ * 41];   // 21 KB: word xw holds x=2xw (lo), 2xw+1 (hi)
  __shared__ float owl[18 * CIN_];         // 9.2 KB
  __shared__ float obl[18];
  const int tid = threadIdx.x;
  const int bid = blockIdx.x;              // 0..1279
  const int xcd = bid & 7;
  const int i0_ = bid >> 3;                // 0..159
  const int b   = (i0_ / 80) * 8 + xcd;
  const int y   = i0_ % 80;
  const bool even = (y & 1) == 0;

  // phase 1: coalesced float4 read along x, packed bf16 write into LDS
  for (int j = tid; j < CIN_ * 20; j += 256) {
    int ci = j / 20, xq = j % 20;
    float4 v = *(const float4*)&x[(((size_t)b * CIN_ + ci) * H_ + y) * W_ + xq * 4];
    ts[ci * 41 + xq * 2 + 0] = pk2(v.x, v.y);
    ts[ci * 41 + xq * 2 + 1] = pk2(v.z, v.w);
  }
  if (even) {
    for (int j = tid; j < 18 * CIN_; j += 256) owl[j] = ow[j];
    if (tid < 18) obl[tid] = ob[tid];
  }
  __syncthreads();

  // phase 2: transpose out of LDS; global stores 256B-contiguous per 32 lanes
  unsigned short* op = xcl + ((size_t)b * H_ * W_ + (size_t)y * W_) * CIN_;
  for (int j = tid; j < 40 * 32; j += 256) {
    int xw = j >> 5, cg = j & 31;          // xw = x-pair, cg = 4-channel group
    unsigned w0 = ts[(cg * 4 + 0) * 41 + xw];
    unsigned w1 = ts[(cg * 4 + 1) * 41 + xw];
    unsigned w2 = ts[(cg * 4 + 2) * 41 + xw];
    unsigned w3 = ts[(cg * 4 + 3) * 41 + xw];
    uint2 lo = make_uint2((w0 & 0xFFFFu) | (w1 << 16),
                          (w2 & 0xFFFFu) | (w3 << 16));
    uint2 hi = make_uint2((w0 >> 16) | (w1 & 0xFFFF0000u),
                          (w2 >> 16) | (w3 & 0xFFFF0000u));
    *(uint2*)(op + (size_t)(2 * xw) * CIN_ + cg * 4)     = lo;
    *(uint2*)(op + (size_t)(2 * xw + 1) * CIN_ + cg * 4) = hi;
  }

  // fused offset conv (even y): x at even positions = low half of word wo
  if (even) {
    const int ho = y >> 1;
    for (int i = tid; i < 18 * WO_; i += 256) {
      int o = i / WO_, wo = i - o * WO_;
      float acc = obl[o];
      const float* wr = &owl[o * CIN_];
#pragma unroll 4
      for (int ci = 0; ci < CIN_; ci++)
        acc += wr[ci] * bu2f((unsigned short)(ts[ci * 41 + wo] & 0xFFFFu));
      off[((b * 18 + o) * HO_ + ho) * WO_ + wo] = acc;
    }
  }
}

// --- K2 v7 "fused": sampling + full-K MFMA GEMM + BN stats in ONE kernel.
// Deletes k_sample_cl and the 59 MB Spk HBM round-trip. Block = 256ch x 64px,
// 400 blocks, 4 waves (2 wch x 2 wpx), wave tile 128ch x 32px (acc[8][2],
// 16 MFMA from 10 ds_read_b128/step). B is built in-kernel: per step each
// wave gathers 4 bilinear corners (16B/lane from L2-resident xcl; reader
// b%8==xcd matches k_cl writer affinity), blends, ds_writes a 1 KB B
// granule-set; 2-buffer B LDS shares it across wch waves (no double gather).
// Gathers for t+1 issue before step t's MFMA phase (latency hidden under
// compute); A keeps the 3-buffer gl_lds pipeline with counted vmcnt(4)
// (issue-order: [blend/write/barrier][GATHER(t+1):4][STAGE_A(t+2):4] ->
// wait(4) at top of t+1 retires gathers+older stages, keeps newest stage
// in flight; t==NKS-1 waits 0). Single raw barrier/step + lgkmcnt(0) before
// it (ds_write visibility); numerics identical to old sampler+gemm contract.
__global__ __launch_bounds__(256) void k_fused(const unsigned short* __restrict__ Apk,
                                               const unsigned short* __restrict__ xcl,
                                               const float* __restrict__ off,
                                               float* __restrict__ out,
                                               float* __restrict__ accum) {
  __shared__ __align__(16) unsigned short a_sh[3][8192];  // 48 KB: 256ch x 32k x3
  __shared__ __align__(16) unsigned short b_sh[2][2048];  // 8 KB:  64px x 32k x2
  __shared__ __align__(16) int   pidx4[576][4];           // 9.2 KB corner idx
  __shared__ __align__(16) float pw4[576][4];             // 9.2 KB corner wts

  const int tid = threadIdx.x;
  const int wv = tid >> 6;
  const int ln = tid & 63;
  const int lm = ln & 15;
  const int qd = ln >> 4;
  const int wch = wv & 1;              // channel half (2)
  const int wpx = wv >> 1;             // pixel half (2)

  const int bid = blockIdx.x;          // 0..399
  const int xcd = bid & 7;
  const int T   = bid >> 3;            // 0..49
  const int b   = xcd + 8 * (T / 25);  // b%8 == xcd: matches k_cl L2 affinity
  const int tl  = T % 25;              // 64-px tile within batch (25*64=1600)

  // ---- meta: 64 px x 9 kk -> 4 corner offsets (abs elem idx) + 4 weights
  for (int j = tid; j < 576; j += 256) {
    int ipx = j / 9, kk = j - ipx * 9;
    int g  = tl * 64 + ipx;            // pixel within batch, 0..1599
    int ho = g / 40, wo = g - ho * 40;
    float dy = off[((b * 18 + 2 * kk) * HO_ + ho) * WO_ + wo];
    float dx = off[((b * 18 + 2 * kk + 1) * HO_ + ho) * WO_ + wo];
    float py  = (float)(2 * ho - 1 + (kk / 3)) + dy;
    float pxf = (float)(2 * wo - 1 + (kk % 3)) + dx;
    float y0f = floorf(py), x0f = floorf(pxf);
    float wy1 = py - y0f, wx1 = pxf - x0f;
    float wy0 = 1.f - wy1, wx0 = 1.f - wx1;
    int y0 = (int)y0f, x0 = (int)x0f;
    int y1 = y0 + 1, x1 = x0 + 1;
    bool vy0 = (y0 >= 0) && (y0 < H_), vy1 = (y1 >= 0) && (y1 < H_);
    bool vx0 = (x0 >= 0) && (x0 < W_), vx1 = (x1 >= 0) && (x1 < W_);
    int y0c = min(max(y0, 0), H_ - 1), y1c = min(max(y1, 0), H_ - 1);
    int x0c = min(max(x0, 0), W_ - 1), x1c = min(max(x1, 0), W_ - 1);
    int base = b * (H_ * W_ * CIN_);
    pidx4[j][0] = base + (y0c * W_ + x0c) * CIN_;  pw4[j][0] = (vy0 && vx0) ? wy0 * wx0 : 0.f;
    pidx4[j][1] = base + (y0c * W_ + x1c) * CIN_;  pw4[j][1] = (vy0 && vx1) ? wy0 * wx1 : 0.f;
    pidx4[j][2] = base + (y1c * W_ + x0c) * CIN_;  pw4[j][2] = (vy1 && vx0) ? wy1 * wx0 : 0.f;
    pidx4[j][3] = base + (y1c * W_ + x1c) * CIN_;  pw4[j][3] = (vy1 && vx1) ? wy1 * wx1 : 0.f;
  }
  __syncthreads();

#define STAGE_A(t, bf) do {                                                    \
    const unsigned short* s_ = Apk + (size_t)(t) * 8192 + wv * 2048 + ln * 8;  \
    gl_lds16(s_ + 0 * 512, &a_sh[bf][wv * 2048 + 0 * 512]);                    \
    gl_lds16(s_ + 1 * 512, &a_sh[bf][wv * 2048 + 1 * 512]);                    \
    gl_lds16(s_ + 2 * 512, &a_sh[bf][wv * 2048 + 2 * 512]);                    \
    gl_lds16(s_ + 3 * 512, &a_sh[bf][wv * 2048 + 3 * 512]);                    \
  } while (0)

// wave wv gathers the B granule-set for pt-group wv: lane (qd,lm) -> px lm,
// channels (t&3)*32 + qd*8 .. +8 of kernel tap t>>2 (old sampler contract).
#define GATHER(t) do {                                                         \
    int kk_ = (t) >> 2, ci0_ = ((t) & 3) * 32;                                 \
    int mi_ = ((wv << 4) + lm) * 9 + kk_;                                      \
    Ig = *(const int4*)&pidx4[mi_][0];                                         \
    Wg = *(const float4*)&pw4[mi_][0];                                         \
    int co_ = ci0_ + qd * 8;                                                   \
    g00 = *(const short8*)(xcl + Ig.x + co_);                                  \
    g01 = *(const short8*)(xcl + Ig.y + co_);                                  \
    g10 = *(const short8*)(xcl + Ig.z + co_);                                  \
    g11 = *(const short8*)(xcl + Ig.w + co_);                                  \
  } while (0)

  floatx4 acc[8][2];
#pragma unroll
  for (int mt = 0; mt < 8; mt++)
#pragma unroll
    for (int nt = 0; nt < 2; nt++) acc[mt][nt] = (floatx4){0.f, 0.f, 0.f, 0.f};

  int4 Ig; float4 Wg; short8 g00, g01, g10, g11;
  const int slot  = (qd + (lm >> 1)) & 3;               // A bank rotation
  const int abase = (wch * 128 + lm) * 32 + slot * 8;   // + mt*512
  const int bbase = (wpx * 2) * 512 + ln * 8;           // + nt*512

  // prologue issue order matters for vmcnt accounting: A(0), G(0), A(1)
  STAGE_A(0, 0);
  GATHER(0);
  STAGE_A(1, 1);

#pragma unroll 1
  for (int t = 0; t < NKS_; t++) {
    // top: A buf[t] + corners(t) retired; newest 4 (= A stage in flight) kept
    if (t == NKS_ - 1) asm volatile("s_waitcnt vmcnt(0)" ::: "memory");
    else               asm volatile("s_waitcnt vmcnt(4)" ::: "memory");

    short8 rb;
#pragma unroll
    for (int i2 = 0; i2 < 8; i2++) {
      float v = Wg.x * bu2f((unsigned short)g00[i2]) +
                Wg.y * bu2f((unsigned short)g01[i2]) +
                Wg.z * bu2f((unsigned short)g10[i2]) +
                Wg.w * bu2f((unsigned short)g11[i2]);
      rb[i2] = (short)f2bu(v);
    }
    *(short8*)&b_sh[t & 1][wv * 512 + ln * 8] = rb;
    asm volatile("s_waitcnt lgkmcnt(0)" ::: "memory");   // ds_write drained
    __builtin_amdgcn_s_barrier();                        // B(t) visible to all

    if (t + 1 < NKS_) GATHER(t + 1);                     // 4 loads, L2 latency
    if (t + 2 < NKS_) STAGE_A(t + 2, (t + 2) % 3);       //   hidden under MFMA

    const unsigned short* al = &a_sh[t % 3][abase];
    const unsigned short* bl = &b_sh[t & 1][bbase];
    short8 av[8], bv[2];
#pragma unroll
    for (int mt = 0; mt < 8; mt++) av[mt] = *(const short8*)(al + mt * 512);
#pragma unroll
    for (int nt = 0; nt < 2; nt++) bv[nt] = *(const short8*)(bl + nt * 512);
#pragma unroll
    for (int mt = 0; mt < 8; mt++)
#pragma unroll
      for (int nt = 0; nt < 2; nt++)
        acc[mt][nt] = __builtin_amdgcn_mfma_f32_16x16x32_bf16(av[mt], bv[nt],
                                                              acc[mt][nt], 0, 0, 0);
  }
#undef STAGE_A
#undef GATHER

  // ---- C write: c = wch*128 + mt*16 + qd*4 + r; px = b*1600 + tl*64 + ...
  const int cb0 = wch * 128;
  float* ob = out + (size_t)b * COUT_ * 1600;
#pragma unroll
  for (int nt = 0; nt < 2; nt++) {
    const int rem = tl * 64 + (wpx * 2 + nt) * 16 + lm;
#pragma unroll
    for (int mt = 0; mt < 8; mt++) {
#pragma unroll
      for (int r = 0; r < 4; r++)
        ob[(size_t)(cb0 + mt * 16 + qd * 4 + r) * 1600 + rem] = acc[mt][nt][r];
    }
  }

  // ---- fused BN stats over this block's 64 px, all 256 ch
  __syncthreads();                      // a_sh dead; reuse as reduction buffer
  float* red = (float*)&a_sh[0][0];     // 512 floats: s1[256], s2[256]
  if (tid < 256) { red[tid] = 0.f; red[256 + tid] = 0.f; }
  __syncthreads();
#pragma unroll
  for (int mt = 0; mt < 8; mt++) {
#pragma unroll
    for (int r = 0; r < 4; r++) {
      float s = acc[mt][0][r] + acc[mt][1][r];
      float q = acc[mt][0][r] * acc[mt][0][r] + acc[mt][1][r] * acc[mt][1][r];
#pragma unroll
      for (int d = 1; d < 16; d <<= 1) {
        s += __shfl_xor(s, d, 16);
        q += __shfl_xor(q, d, 16);
      }
      if (lm == 0) {
        int lc = cb0 + mt * 16 + qd * 4 + r;
        atomicAdd(&red[lc], s);
        atomicAdd(&red[256 + lc], q);
      }
    }
  }
  __syncthreads();
  if (tid < 256) {
    atomicAdd(&accum[tid],         red[tid]);
    atomicAdd(&accum[COUT_ + tid], red[256 + tid]);
  }
}

// --------------------------- K3: BN + SiLU in place on the final out buffer
__global__ __launch_bounds__(256) void k_bn(float* __restrict__ io0,
                                            const float* __restrict__ accum,
                                            const float* __restrict__ gamma,
                                            const float* __restrict__ beta) {
  const int t = blockIdx.x * 256 + threadIdx.x;
  const int i0 = t * 4;
  const int c = (i0 / (HO_ * WO_)) % COUT_;
  const float mean = accum[c] * (1.f / NPIX_);
  const float var  = accum[COUT_ + c] * (1.f / NPIX_) - mean * mean;
  const float inv  = rsqrtf(var + 1e-5f);
  const float g  = gamma[c] * inv;
  const float be = beta[c] - mean * g;
  float4 r0 = *(const float4*)(io0 + i0);
  float v[4] = {r0.x, r0.y, r0.z, r0.w};
#pragma unroll
  for (int q = 0; q < 4; q++) {
    float u = v[q] * g + be;
    v[q] = u / (1.f + expf(-u));
  }
  *(float4*)(io0 + i0) = make_float4(v[0], v[1], v[2], v[3]);
}

// ----------------------------------------------------------------- launcher
extern "C" void kernel_launch(void* const* d_in, const int* in_sizes, int n_in,
                              void* d_out, int out_size, void* d_ws, size_t ws_size,
                              hipStream_t stream) {
  const float* x     = (const float*)d_in[0];
  const float* ow    = (const float*)d_in[1];
  const float* ob    = (const float*)d_in[2];
  const float* dw    = (const float*)d_in[3];
  const float* gamma = (const float*)d_in[5];
  const float* beta  = (const float*)d_in[6];
  float* out = (float*)d_out;

  float* off   = (float*)d_ws;                                 // 460800 f
  float* accum = off + B_ * 18 * HO_ * WO_;                    // 512 f
  unsigned short* Apk = (unsigned short*)(accum + 2 * COUT_);  // 294912 us
  unsigned short* xcl = Apk + (size_t)SK_ * COUT_;             // 13107200 us

  k_pack<<<SK_, 256, 0, stream>>>(dw, Apk, accum);
  k_cl<<<B_ * H_, 256, 0, stream>>>(x, ow, ob, xcl, off);
  k_fused<<<400, 256, 0, stream>>>(Apk, xcl, off, out, accum);
  k_bn<<<(NPIX_ * COUT_ / 4 + 255) / 256, 256, 0, stream>>>(
      out, accum, gamma, beta);
}